// Round 7
// baseline (1478.819 us; speedup 1.0000x reference)
//
#include <hip/hip_runtime.h>
#include <hip/hip_bf16.h>

#define D 128
#define OSTR 136   // LDS row stride (shorts) for epilogue transpose
#define CHUNK 12544  // per-XCD node chunk (multiple of 64); 8*12544 >= N

typedef float f32x4  __attribute__((ext_vector_type(4)));
typedef unsigned int u32x4 __attribute__((ext_vector_type(4)));
typedef __attribute__((ext_vector_type(8))) __bf16 bh8;

union UV { uint4 u; bh8 h; };

__device__ inline float bf2f(unsigned short u) {
    union { unsigned int i; float f; } x; x.i = ((unsigned int)u) << 16; return x.f;
}
__device__ inline unsigned short f2bf(float f) {
    union { float f; unsigned int i; } x; x.f = f;
    return (unsigned short)((x.i + 0x7fffu + ((x.i >> 16) & 1u)) >> 16);
}
__device__ inline void acc2(unsigned int u, float& a, float& b) {
    union { unsigned int i; float f; } lo, hi;
    lo.i = u << 16; hi.i = u & 0xffff0000u;
    a += lo.f; b += hi.f;
}
__device__ inline unsigned int addb2(unsigned int ua, unsigned int ub) {
    union { unsigned int i; float f; } la, ha, lb, hb;
    la.i = ua << 16; ha.i = ua & 0xffff0000u;
    lb.i = ub << 16; hb.i = ub & 0xffff0000u;
    return ((unsigned int)f2bf(ha.f + hb.f) << 16) | f2bf(la.f + lb.f);
}

// ---------------- CSR build ----------------
__global__ void k_hist(const int* __restrict__ edges, int E, int* __restrict__ deg) {
    int e = blockIdx.x * blockDim.x + threadIdx.x;
    if (e < E) {
        atomicAdd(&deg[edges[2 * e]], 1);
        atomicAdd(&deg[edges[2 * e + 1]], 1);
    }
}

__global__ void k_scan1(const int* __restrict__ deg, int n,
                        int* __restrict__ incl, int* __restrict__ bsum) {
    __shared__ int lds[1024];
    int t = threadIdx.x;
    int i = blockIdx.x * 1024 + t;
    int v = (i < n) ? deg[i] : 0;
    int cur = v;
    lds[t] = cur;
    __syncthreads();
    for (int off = 1; off < 1024; off <<= 1) {
        int add = (t >= off) ? lds[t - off] : 0;
        __syncthreads();
        cur += add;
        lds[t] = cur;
        __syncthreads();
    }
    if (i < n) incl[i] = cur;
    if (t == 1023) bsum[blockIdx.x] = cur;
}

__global__ void k_scan2(int* __restrict__ bsum, int nb) {
    __shared__ int lds[128];
    int t = threadIdx.x;
    int v = (t < nb) ? bsum[t] : 0;
    int cur = v;
    lds[t] = cur;
    __syncthreads();
    for (int off = 1; off < 128; off <<= 1) {
        int add = (t >= off) ? lds[t - off] : 0;
        __syncthreads();
        cur += add;
        lds[t] = cur;
        __syncthreads();
    }
    if (t < nb) bsum[t] = cur - v;  // exclusive
}

__global__ void k_scan3(const int* __restrict__ incl, const int* __restrict__ deg,
                        const int* __restrict__ bsum, int n, int twoE,
                        int* __restrict__ rowstart, int* __restrict__ cursor) {
    int i = blockIdx.x * blockDim.x + threadIdx.x;
    if (i < n) {
        int r = incl[i] - deg[i] + bsum[i >> 10];
        rowstart[i] = r;
        cursor[i] = r;
    }
    if (i == 0) rowstart[n] = twoE;
}

__global__ void k_fill(const int* __restrict__ edges, int E,
                       int* __restrict__ cursor, int* __restrict__ adj) {
    int e = blockIdx.x * blockDim.x + threadIdx.x;
    if (e < E) {
        int a = edges[2 * e], b = edges[2 * e + 1];
        adj[atomicAdd(&cursor[a], 1)] = b;
        adj[atomicAdd(&cursor[b], 1)] = a;
    }
}

// ---------------- weight prep: bf16, K-chunked layout ----------------
// wb[l][chunk=kk>>5][o][kk&31], kk = m*128+k (m=0: W0, m=1: W1)
__global__ void k_wprep(const float* __restrict__ W0_1, const float* __restrict__ W1_1,
                        const float* __restrict__ W0_h, const float* __restrict__ W1_h,
                        unsigned short* __restrict__ wb) {
    int idx = blockIdx.x * 256 + threadIdx.x;
    if (idx >= 13 * 2 * 128 * 128) return;
    int k = idx & 127;
    int o = (idx >> 7) & 127;
    int m = (idx >> 14) & 1;
    int l = idx >> 15;
    const float* src = (l == 0) ? (m ? W1_1 : W0_1)
                                : ((m ? W1_h : W0_h) + (size_t)(l - 1) * 16384);
    float v = src[o * 128 + k];
    int kk = m * 128 + k;
    wb[(size_t)l * 32768 + (kk >> 5) * 4096 + o * 32 + (kk & 31)] = f2bf(v);
}

// ---------------- fp32 -> bf16 convert ----------------
__global__ void k_cvt(const float* __restrict__ in, unsigned short* __restrict__ out, int n4) {
    int i = blockIdx.x * blockDim.x + threadIdx.x;
    if (i >= n4) return;
    f32x4 v = *(const f32x4*)&in[(size_t)i * 4];
    unsigned short u[4];
    #pragma unroll
    for (int j = 0; j < 4; ++j) u[j] = f2bf(v[j]);
    *(uint2*)&out[(size_t)i * 4] = *(uint2*)u;
}

// ---------------- neighbor aggregation (bf16 in/out, fp32 accum) ----------------
// wave per node; XCD-chunked node mapping (producer/consumer same XCD for sb).
// Gather row loads are NONTEMPORAL: per-XCD reuse of a random row is <1 and the
// 25.6MB stream only thrashes sb/adj out of the 4MB L2.
__global__ __launch_bounds__(256) void k_agg(
    const unsigned short* __restrict__ x, const int* __restrict__ rowstart,
    const int* __restrict__ adj, unsigned short* __restrict__ s, int n) {
    int node = (blockIdx.x & 7) * CHUNK + (blockIdx.x >> 3) * 4 + (threadIdx.x >> 6);
    int lane = threadIdx.x & 63;
    if (node >= n) return;
    int r0 = rowstart[node], r1 = rowstart[node + 1];
    float a[8], b[8];
    #pragma unroll
    for (int k = 0; k < 8; ++k) { a[k] = 0.f; b[k] = 0.f; }
    for (int p = r0; p < r1; p += 8) {
        int q = p + (lane & 7);
        int idx = (q < r1) ? adj[q] : 0;
        unsigned int u[8];
        #pragma unroll
        for (int k = 0; k < 8; ++k) {
            int j = __shfl(idx, k);
            u[k] = __builtin_nontemporal_load(
                (const unsigned int*)&x[(size_t)j * D + lane * 2]);
        }
        #pragma unroll
        for (int k = 0; k < 8; ++k)
            if (p + k < r1) acc2(u[k], a[k], b[k]);
    }
    float f0 = ((a[0] + a[1]) + (a[2] + a[3])) + ((a[4] + a[5]) + (a[6] + a[7]));
    float f1 = ((b[0] + b[1]) + (b[2] + b[3])) + ((b[4] + b[5]) + (b[6] + b[7]));
    unsigned int out = ((unsigned int)f2bf(f1) << 16) | f2bf(f0);
    *(unsigned int*)&s[(size_t)node * D + lane * 2] = out;
}

// ---------------- MFMA GEMM: 64x128 tile, 2-stage register pipeline ----------------
// out[i][o] = act([x_i, s_i] @ [W0T;W1T] + b0 + deg*b1)
// 256 threads = 4 waves; block tile 64 nodes x 128 outs; K=256 in 8 chunks of 32.
// The kc loop is software-pipelined in REGISTERS: while MFMAs consume stage cs,
// the 6 fragment loads of kc+1 are already issued into stage cs^1 — forcing the
// compiler to keep ~12 16B loads in flight (round-6's VGPR=44 showed it kept
// only a handful). No LDS, no barriers in the main loop.
__global__ __launch_bounds__(256) void k_gemm(
    const unsigned short* __restrict__ x,   // [n][128] bf16
    const unsigned short* __restrict__ s,   // [n][128] bf16
    const unsigned short* __restrict__ wb,  // layer weights, chunked [8][128][32] bf16
    const float* __restrict__ b0, const float* __restrict__ b1,
    const int* __restrict__ deg,
    unsigned short* __restrict__ out,       // [n][128] bf16
    float* __restrict__ out32,              // optional fp32 copy (aux), may be null
    const unsigned short* __restrict__ resid, // optional residual input (bf16)
    unsigned short* __restrict__ zout,      // optional: zout = out + resid
    int n, int do_relu) {
    __shared__ __align__(16) unsigned short LDS[64 * OSTR];  // 17408 B (epilogue only)
    int node0 = (blockIdx.x & 7) * CHUNK + (blockIdx.x >> 3) * 64;
    if (node0 >= n) return;
    int t = threadIdx.x;
    int lane = t & 63;
    int wave = t >> 6;
    int wm = (wave >> 1) * 32;
    int wn = (wave & 1) * 64;
    int mlane = lane & 15;
    int quad = lane >> 4;

    f32x4 acc[2][4];
    #pragma unroll
    for (int i = 0; i < 2; ++i)
        #pragma unroll
        for (int j = 0; j < 4; ++j) acc[i][j] = (f32x4){0.f, 0.f, 0.f, 0.f};

    uint4 ra[2][2];
    bh8 rb[2][4];
    auto LDK = [&](int kc, int st) {
        const unsigned short* srcA = (kc < 4) ? x : s;
        int kbase = (kc & 3) * 32;
        #pragma unroll
        for (int i = 0; i < 2; ++i) {
            int g = node0 + wm + i * 16 + mlane;
            uint4 v = {0u, 0u, 0u, 0u};
            if (g < n) v = *(const uint4*)&srcA[(size_t)g * D + kbase + quad * 8];
            ra[st][i] = v;
        }
        #pragma unroll
        for (int j = 0; j < 4; ++j)
            rb[st][j] = *(const bh8*)&wb[(size_t)kc * 4096 + (wn + j * 16 + mlane) * 32 + quad * 8];
    };

    LDK(0, 0);
    #pragma unroll
    for (int kc = 0; kc < 8; ++kc) {
        int cs = kc & 1;
        if (kc < 7) LDK(kc + 1, cs ^ 1);   // issue next-chunk loads before MFMAs
        bh8 a0, a1;
        { UV v; v.u = ra[cs][0]; a0 = v.h; }
        { UV v; v.u = ra[cs][1]; a1 = v.h; }
        #pragma unroll
        for (int j = 0; j < 4; ++j) {
            acc[0][j] = __builtin_amdgcn_mfma_f32_16x16x32_bf16(a0, rb[cs][j], acc[0][j], 0, 0, 0);
            acc[1][j] = __builtin_amdgcn_mfma_f32_16x16x32_bf16(a1, rb[cs][j], acc[1][j], 0, 0, 0);
        }
    }

    // ---- epilogue: bias + deg*b1 + relu -> LDS transpose -> coalesced nt stores ----
    #pragma unroll
    for (int i = 0; i < 2; ++i) {
        int mrow = wm + i * 16 + quad * 4;
        #pragma unroll
        for (int j = 0; j < 4; ++j) {
            int nn = wn + j * 16 + mlane;
            float b0v = b0[nn], b1v = b1[nn];
            #pragma unroll
            for (int r = 0; r < 4; ++r) {
                int g = node0 + mrow + r;
                float dg = (g < n) ? (float)deg[g] : 0.f;
                float val = acc[i][j][r] + b0v + dg * b1v;
                if (do_relu) val = fmaxf(val, 0.f);
                LDS[(mrow + r) * OSTR + nn] = f2bf(val);
            }
        }
    }
    __syncthreads();
    // bf16 store: 4 passes, 16 lanes x 16B = one full 256B node row per 16 threads
    #pragma unroll
    for (int pass = 0; pass < 4; ++pass) {
        int row = pass * 16 + (t >> 4);
        int seg = (t & 15) * 8;
        int g = node0 + row;
        if (g < n) {
            u32x4 v = *(const u32x4*)&LDS[row * OSTR + seg];
            __builtin_nontemporal_store(v, (u32x4*)&out[(size_t)g * D + seg]);
            if (zout) {
                u32x4 rr = *(const u32x4*)&resid[(size_t)g * D + seg];
                u32x4 zz;
                zz.x = addb2(v.x, rr.x);
                zz.y = addb2(v.y, rr.y);
                zz.z = addb2(v.z, rr.z);
                zz.w = addb2(v.w, rr.w);
                __builtin_nontemporal_store(zz, (u32x4*)&zout[(size_t)g * D + seg]);
            }
        }
    }
    if (out32) {
        #pragma unroll
        for (int pass = 0; pass < 8; ++pass) {
            int row = pass * 8 + (t >> 5);
            int seg = (t & 31) * 4;
            int g = node0 + row;
            if (g < n) {
                f32x4 v;
                #pragma unroll
                for (int j = 0; j < 4; ++j) v[j] = bf2f(LDS[row * OSTR + seg + j]);
                __builtin_nontemporal_store(v, (f32x4*)&out32[(size_t)g * D + seg]);
            }
        }
    }
}

// ---------------- fused final layer: aggregate in registers + D_out=3 dot ----------------
// wave per node. Gathers s = sum_j z_j into registers (lane holds cols 2l, 2l+1),
// then vert[o] = sum_k z_k*W0[o,k] + s_k*W1[o,k] + b0[o] + deg*b1[o] via shuffle
// reduce. Deletes the final sb write+read (50MB of L3 traffic) and one dispatch.
__global__ __launch_bounds__(256) void k_lastagg(
    const unsigned short* __restrict__ z, const int* __restrict__ rowstart,
    const int* __restrict__ adj,
    const float* __restrict__ W0, const float* __restrict__ b0,
    const float* __restrict__ W1, const float* __restrict__ b1,
    float* __restrict__ vert, int n) {
    int node = blockIdx.x * 4 + (threadIdx.x >> 6);
    int lane = threadIdx.x & 63;
    if (node >= n) return;
    int r0 = rowstart[node], r1 = rowstart[node + 1];
    float a[8], b[8];
    #pragma unroll
    for (int k = 0; k < 8; ++k) { a[k] = 0.f; b[k] = 0.f; }
    for (int p = r0; p < r1; p += 8) {
        int q = p + (lane & 7);
        int idx = (q < r1) ? adj[q] : 0;
        unsigned int u[8];
        #pragma unroll
        for (int k = 0; k < 8; ++k) {
            int j = __shfl(idx, k);
            u[k] = __builtin_nontemporal_load(
                (const unsigned int*)&z[(size_t)j * D + lane * 2]);
        }
        #pragma unroll
        for (int k = 0; k < 8; ++k)
            if (p + k < r1) acc2(u[k], a[k], b[k]);
    }
    float f0 = ((a[0] + a[1]) + (a[2] + a[3])) + ((a[4] + a[5]) + (a[6] + a[7]));
    float f1 = ((b[0] + b[1]) + (b[2] + b[3])) + ((b[4] + b[5]) + (b[6] + b[7]));
    // own row z[node], cols 2l, 2l+1
    unsigned int zz = *(const unsigned int*)&z[(size_t)node * D + lane * 2];
    float z0, z1;
    { union { unsigned int i; float f; } lo, hi;
      lo.i = zz << 16; hi.i = zz & 0xffff0000u; z0 = lo.f; z1 = hi.f; }
    float dg = (float)(r1 - r0);
    #pragma unroll
    for (int o = 0; o < 3; ++o) {
        float p = z0 * W0[o * D + 2 * lane] + z1 * W0[o * D + 2 * lane + 1]
                + f0 * W1[o * D + 2 * lane] + f1 * W1[o * D + 2 * lane + 1];
        for (int off = 32; off > 0; off >>= 1) p += __shfl_down(p, off);
        if (lane == 0) vert[(size_t)node * 3 + o] = p + b0[o] + dg * b1[o];
    }
}

extern "C" void kernel_launch(void* const* d_in, const int* in_sizes, int n_in,
                              void* d_out, int out_size, void* d_ws, size_t ws_size,
                              hipStream_t stream) {
    const float* features = (const float*)d_in[0];
    const int*   edges    = (const int*)d_in[1];
    const float* W0_1 = (const float*)d_in[2];
    const float* b0_1 = (const float*)d_in[3];
    const float* W1_1 = (const float*)d_in[4];
    const float* b1_1 = (const float*)d_in[5];
    const float* W0_h = (const float*)d_in[6];
    const float* b0_h = (const float*)d_in[7];
    const float* W1_h = (const float*)d_in[8];
    const float* b1_h = (const float*)d_in[9];
    const float* W0_l = (const float*)d_in[10];
    const float* b0_l = (const float*)d_in[11];
    const float* W1_l = (const float*)d_in[12];
    const float* b1_l = (const float*)d_in[13];

    const int N_ = 100000, E_ = 300000;
    float* vert = (float*)d_out;                    // N*3
    float* aux  = (float*)d_out + (size_t)N_ * 3;   // N*128 fp32

    char* w = (char*)d_ws;
    auto alloc = [&](size_t bytes) {
        char* p = w;
        w += (bytes + 255) & ~(size_t)255;
        return p;
    };
    unsigned short* wb    = (unsigned short*)alloc((size_t)13 * 32768 * 2);
    unsigned short* xf    = (unsigned short*)alloc((size_t)N_ * D * 2);
    unsigned short* resid = (unsigned short*)alloc((size_t)N_ * D * 2);
    unsigned short* xa    = (unsigned short*)alloc((size_t)N_ * D * 2);
    unsigned short* xb    = (unsigned short*)alloc((size_t)N_ * D * 2);
    unsigned short* sb    = (unsigned short*)alloc((size_t)N_ * D * 2);
    int* deg    = (int*)alloc((size_t)N_ * 4);
    int* incl   = (int*)alloc((size_t)N_ * 4);
    int* rowst  = (int*)alloc((size_t)(N_ + 1) * 4);
    int* cursor = (int*)alloc((size_t)N_ * 4);
    int* bsum   = (int*)alloc(128 * 4);
    int* adj    = (int*)alloc((size_t)2 * E_ * 4);

    // CSR build
    hipMemsetAsync(deg, 0, (size_t)N_ * 4, stream);
    k_hist<<<(E_ + 255) / 256, 256, 0, stream>>>(edges, E_, deg);
    int nb = (N_ + 1023) / 1024;   // 98
    k_scan1<<<nb, 1024, 0, stream>>>(deg, N_, incl, bsum);
    k_scan2<<<1, 128, 0, stream>>>(bsum, nb);
    k_scan3<<<(N_ + 255) / 256, 256, 0, stream>>>(incl, deg, bsum, N_, 2 * E_, rowst, cursor);
    k_fill<<<(E_ + 255) / 256, 256, 0, stream>>>(edges, E_, cursor, adj);

    // weight + feature conversion
    k_wprep<<<(13 * 2 * 16384 + 255) / 256, 256, 0, stream>>>(W0_1, W1_1, W0_h, W1_h, wb);
    k_cvt<<<(N_ * D / 4 + 255) / 256, 256, 0, stream>>>(features, xf, N_ * D / 4);

    // XCD-chunked grids: xcd = blockIdx%8, chunk = CHUNK nodes
    int gblocks = 8 * ((CHUNK) / 64);    // 8 * 196 = 1568
    int ablocks = 8 * ((CHUNK) / 4);     // 8 * 3136 = 25088
    int lblocks = (N_ + 3) / 4;          // k_lastagg

    // layer 1: xf -> resid
    k_agg<<<ablocks, 256, 0, stream>>>(xf, rowst, adj, sb, N_);
    k_gemm<<<gblocks, 256, 0, stream>>>(xf, sb, wb, b0_1, b1_1, deg, resid,
                                        nullptr, nullptr, nullptr, N_, 1);

    // 12 hidden layers; layer 12 also writes aux (fp32) and z = resid + x12 -> xf
    for (int h = 0; h < 12; ++h) {
        const unsigned short* in = (h == 0) ? resid : ((h & 1) ? xa : xb);
        unsigned short* outp = (h & 1) ? xb : xa;
        float* o32 = (h == 11) ? aux : nullptr;
        const unsigned short* radd = (h == 11) ? resid : nullptr;
        unsigned short* zo = (h == 11) ? xf : nullptr;
        k_agg<<<ablocks, 256, 0, stream>>>(in, rowst, adj, sb, N_);
        k_gemm<<<gblocks, 256, 0, stream>>>(in, sb, wb + (size_t)(1 + h) * 32768,
                                            b0_h + h * 128, b1_h + h * 128, deg,
                                            outp, o32, radd, zo, N_, 1);
    }

    // last layer fused: z (in xf) -> vertices, aggregation kept in registers
    k_lastagg<<<lblocks, 256, 0, stream>>>(xf, rowst, adj, W0_l, b0_l, W1_l, b1_l,
                                           vert, N_);
}

// Round 8
// 1197.503 us; speedup vs baseline: 1.2349x; 1.2349x over previous
//
#include <hip/hip_runtime.h>
#include <hip/hip_bf16.h>

#define D 128
#define OSTR 136   // LDS row stride (shorts) for epilogue transpose
#define CHUNK 12544  // per-XCD node chunk (multiple of 64); 8*12544 >= N

typedef float f32x4  __attribute__((ext_vector_type(4)));
typedef unsigned int u32x4 __attribute__((ext_vector_type(4)));
typedef __attribute__((ext_vector_type(8))) __bf16 bh8;

union UV { uint4 u; bh8 h; };

__device__ inline float bf2f(unsigned short u) {
    union { unsigned int i; float f; } x; x.i = ((unsigned int)u) << 16; return x.f;
}
__device__ inline unsigned short f2bf(float f) {
    union { float f; unsigned int i; } x; x.f = f;
    return (unsigned short)((x.i + 0x7fffu + ((x.i >> 16) & 1u)) >> 16);
}
__device__ inline void acc2(unsigned int u, float& a, float& b) {
    union { unsigned int i; float f; } lo, hi;
    lo.i = u << 16; hi.i = u & 0xffff0000u;
    a += lo.f; b += hi.f;
}
__device__ inline unsigned int addb2(unsigned int ua, unsigned int ub) {
    union { unsigned int i; float f; } la, ha, lb, hb;
    la.i = ua << 16; ha.i = ua & 0xffff0000u;
    lb.i = ub << 16; hb.i = ub & 0xffff0000u;
    return ((unsigned int)f2bf(ha.f + hb.f) << 16) | f2bf(la.f + lb.f);
}

// ---------------- CSR build ----------------
__global__ void k_hist(const int* __restrict__ edges, int E, int* __restrict__ deg) {
    int e = blockIdx.x * blockDim.x + threadIdx.x;
    if (e < E) {
        atomicAdd(&deg[edges[2 * e]], 1);
        atomicAdd(&deg[edges[2 * e + 1]], 1);
    }
}

__global__ void k_scan1(const int* __restrict__ deg, int n,
                        int* __restrict__ incl, int* __restrict__ bsum) {
    __shared__ int lds[1024];
    int t = threadIdx.x;
    int i = blockIdx.x * 1024 + t;
    int v = (i < n) ? deg[i] : 0;
    int cur = v;
    lds[t] = cur;
    __syncthreads();
    for (int off = 1; off < 1024; off <<= 1) {
        int add = (t >= off) ? lds[t - off] : 0;
        __syncthreads();
        cur += add;
        lds[t] = cur;
        __syncthreads();
    }
    if (i < n) incl[i] = cur;
    if (t == 1023) bsum[blockIdx.x] = cur;
}

__global__ void k_scan2(int* __restrict__ bsum, int nb) {
    __shared__ int lds[128];
    int t = threadIdx.x;
    int v = (t < nb) ? bsum[t] : 0;
    int cur = v;
    lds[t] = cur;
    __syncthreads();
    for (int off = 1; off < 128; off <<= 1) {
        int add = (t >= off) ? lds[t - off] : 0;
        __syncthreads();
        cur += add;
        lds[t] = cur;
        __syncthreads();
    }
    if (t < nb) bsum[t] = cur - v;  // exclusive
}

__global__ void k_scan3(const int* __restrict__ incl, const int* __restrict__ deg,
                        const int* __restrict__ bsum, int n, int twoE,
                        int* __restrict__ rowstart, int* __restrict__ cursor) {
    int i = blockIdx.x * blockDim.x + threadIdx.x;
    if (i < n) {
        int r = incl[i] - deg[i] + bsum[i >> 10];
        rowstart[i] = r;
        cursor[i] = r;
    }
    if (i == 0) rowstart[n] = twoE;
}

__global__ void k_fill(const int* __restrict__ edges, int E,
                       int* __restrict__ cursor, int* __restrict__ adj) {
    int e = blockIdx.x * blockDim.x + threadIdx.x;
    if (e < E) {
        int a = edges[2 * e], b = edges[2 * e + 1];
        adj[atomicAdd(&cursor[a], 1)] = b;
        adj[atomicAdd(&cursor[b], 1)] = a;
    }
}

// ---------------- weight prep: bf16, K-chunked layout ----------------
// wb[l][chunk=kk>>5][o][kk&31], kk = m*128+k (m=0: W0, m=1: W1)
__global__ void k_wprep(const float* __restrict__ W0_1, const float* __restrict__ W1_1,
                        const float* __restrict__ W0_h, const float* __restrict__ W1_h,
                        unsigned short* __restrict__ wb) {
    int idx = blockIdx.x * 256 + threadIdx.x;
    if (idx >= 13 * 2 * 128 * 128) return;
    int k = idx & 127;
    int o = (idx >> 7) & 127;
    int m = (idx >> 14) & 1;
    int l = idx >> 15;
    const float* src = (l == 0) ? (m ? W1_1 : W0_1)
                                : ((m ? W1_h : W0_h) + (size_t)(l - 1) * 16384);
    float v = src[o * 128 + k];
    int kk = m * 128 + k;
    wb[(size_t)l * 32768 + (kk >> 5) * 4096 + o * 32 + (kk & 31)] = f2bf(v);
}

// ---------------- fp32 -> bf16 convert ----------------
__global__ void k_cvt(const float* __restrict__ in, unsigned short* __restrict__ out, int n4) {
    int i = blockIdx.x * blockDim.x + threadIdx.x;
    if (i >= n4) return;
    f32x4 v = *(const f32x4*)&in[(size_t)i * 4];
    unsigned short u[4];
    #pragma unroll
    for (int j = 0; j < 4; ++j) u[j] = f2bf(v[j]);
    *(uint2*)&out[(size_t)i * 4] = *(uint2*)u;
}

// ---------------- neighbor aggregation (bf16 in/out, fp32 accum) ----------------
// wave per node; XCD-chunked node mapping (producer/consumer same XCD for sb).
// Gather loads are CACHED: each x-row is read by deg≈6 neighbors and the whole
// 25.6MB input is L3-resident — nt loads here cost +200µs total (round 7).
__global__ __launch_bounds__(256) void k_agg(
    const unsigned short* __restrict__ x, const int* __restrict__ rowstart,
    const int* __restrict__ adj, unsigned short* __restrict__ s, int n) {
    int node = (blockIdx.x & 7) * CHUNK + (blockIdx.x >> 3) * 4 + (threadIdx.x >> 6);
    int lane = threadIdx.x & 63;
    if (node >= n) return;
    int r0 = rowstart[node], r1 = rowstart[node + 1];
    float a[8], b[8];
    #pragma unroll
    for (int k = 0; k < 8; ++k) { a[k] = 0.f; b[k] = 0.f; }
    for (int p = r0; p < r1; p += 8) {
        int q = p + (lane & 7);
        int idx = (q < r1) ? adj[q] : 0;
        unsigned int u[8];
        #pragma unroll
        for (int k = 0; k < 8; ++k) {
            int j = __shfl(idx, k);
            u[k] = *(const unsigned int*)&x[(size_t)j * D + lane * 2];
        }
        #pragma unroll
        for (int k = 0; k < 8; ++k)
            if (p + k < r1) acc2(u[k], a[k], b[k]);
    }
    float f0 = ((a[0] + a[1]) + (a[2] + a[3])) + ((a[4] + a[5]) + (a[6] + a[7]));
    float f1 = ((b[0] + b[1]) + (b[2] + b[3])) + ((b[4] + b[5]) + (b[6] + b[7]));
    unsigned int out = ((unsigned int)f2bf(f1) << 16) | f2bf(f0);
    *(unsigned int*)&s[(size_t)node * D + lane * 2] = out;
}

// ---------------- MFMA GEMM: 64x128 tile, 2-stage register pipeline ----------------
// out[i][o] = act([x_i, s_i] @ [W0T;W1T] + b0 + deg*b1)
// 256 threads = 4 waves; block tile 64 nodes x 128 outs; K=256 in 8 chunks of 32.
// kc loop software-pipelined in REGISTERS: while MFMAs consume stage cs, the 6
// fragment loads of kc+1 are already in flight into stage cs^1. No LDS/barriers
// in the main loop. All stores CACHED (out is 6x-reused by next layer's gather).
__global__ __launch_bounds__(256) void k_gemm(
    const unsigned short* __restrict__ x,   // [n][128] bf16
    const unsigned short* __restrict__ s,   // [n][128] bf16
    const unsigned short* __restrict__ wb,  // layer weights, chunked [8][128][32] bf16
    const float* __restrict__ b0, const float* __restrict__ b1,
    const int* __restrict__ deg,
    unsigned short* __restrict__ out,       // [n][128] bf16
    float* __restrict__ out32,              // optional fp32 copy (aux), may be null
    const unsigned short* __restrict__ resid, // optional residual input (bf16)
    unsigned short* __restrict__ zout,      // optional: zout = out + resid
    int n, int do_relu) {
    __shared__ __align__(16) unsigned short LDS[64 * OSTR];  // 17408 B (epilogue only)
    int node0 = (blockIdx.x & 7) * CHUNK + (blockIdx.x >> 3) * 64;
    if (node0 >= n) return;
    int t = threadIdx.x;
    int lane = t & 63;
    int wave = t >> 6;
    int wm = (wave >> 1) * 32;
    int wn = (wave & 1) * 64;
    int mlane = lane & 15;
    int quad = lane >> 4;

    f32x4 acc[2][4];
    #pragma unroll
    for (int i = 0; i < 2; ++i)
        #pragma unroll
        for (int j = 0; j < 4; ++j) acc[i][j] = (f32x4){0.f, 0.f, 0.f, 0.f};

    uint4 ra[2][2];
    bh8 rb[2][4];
    auto LDK = [&](int kc, int st) {
        const unsigned short* srcA = (kc < 4) ? x : s;
        int kbase = (kc & 3) * 32;
        #pragma unroll
        for (int i = 0; i < 2; ++i) {
            int g = node0 + wm + i * 16 + mlane;
            uint4 v = {0u, 0u, 0u, 0u};
            if (g < n) v = *(const uint4*)&srcA[(size_t)g * D + kbase + quad * 8];
            ra[st][i] = v;
        }
        #pragma unroll
        for (int j = 0; j < 4; ++j)
            rb[st][j] = *(const bh8*)&wb[(size_t)kc * 4096 + (wn + j * 16 + mlane) * 32 + quad * 8];
    };

    LDK(0, 0);
    #pragma unroll
    for (int kc = 0; kc < 8; ++kc) {
        int cs = kc & 1;
        if (kc < 7) LDK(kc + 1, cs ^ 1);   // issue next-chunk loads before MFMAs
        bh8 a0, a1;
        { UV v; v.u = ra[cs][0]; a0 = v.h; }
        { UV v; v.u = ra[cs][1]; a1 = v.h; }
        #pragma unroll
        for (int j = 0; j < 4; ++j) {
            acc[0][j] = __builtin_amdgcn_mfma_f32_16x16x32_bf16(a0, rb[cs][j], acc[0][j], 0, 0, 0);
            acc[1][j] = __builtin_amdgcn_mfma_f32_16x16x32_bf16(a1, rb[cs][j], acc[1][j], 0, 0, 0);
        }
    }

    // ---- epilogue: bias + deg*b1 + relu -> LDS transpose -> coalesced stores ----
    #pragma unroll
    for (int i = 0; i < 2; ++i) {
        int mrow = wm + i * 16 + quad * 4;
        #pragma unroll
        for (int j = 0; j < 4; ++j) {
            int nn = wn + j * 16 + mlane;
            float b0v = b0[nn], b1v = b1[nn];
            #pragma unroll
            for (int r = 0; r < 4; ++r) {
                int g = node0 + mrow + r;
                float dg = (g < n) ? (float)deg[g] : 0.f;
                float val = acc[i][j][r] + b0v + dg * b1v;
                if (do_relu) val = fmaxf(val, 0.f);
                LDS[(mrow + r) * OSTR + nn] = f2bf(val);
            }
        }
    }
    __syncthreads();
    // bf16 store: 4 passes, 16 lanes x 16B = one full 256B node row per 16 threads
    #pragma unroll
    for (int pass = 0; pass < 4; ++pass) {
        int row = pass * 16 + (t >> 4);
        int seg = (t & 15) * 8;
        int g = node0 + row;
        if (g < n) {
            u32x4 v = *(const u32x4*)&LDS[row * OSTR + seg];
            *(u32x4*)&out[(size_t)g * D + seg] = v;
            if (zout) {
                u32x4 rr = *(const u32x4*)&resid[(size_t)g * D + seg];
                u32x4 zz;
                zz.x = addb2(v.x, rr.x);
                zz.y = addb2(v.y, rr.y);
                zz.z = addb2(v.z, rr.z);
                zz.w = addb2(v.w, rr.w);
                *(u32x4*)&zout[(size_t)g * D + seg] = zz;
            }
        }
    }
    if (out32) {
        #pragma unroll
        for (int pass = 0; pass < 8; ++pass) {
            int row = pass * 8 + (t >> 5);
            int seg = (t & 31) * 4;
            int g = node0 + row;
            if (g < n) {
                f32x4 v;
                #pragma unroll
                for (int j = 0; j < 4; ++j) v[j] = bf2f(LDS[row * OSTR + seg + j]);
                *(f32x4*)&out32[(size_t)g * D + seg] = v;
            }
        }
    }
}

// ---------------- fused final layer: aggregate in registers + D_out=3 dot ----------------
// wave per node. Gathers s = sum_j z_j into registers (lane holds cols 2l, 2l+1),
// then vert[o] = sum_k z_k*W0[o,k] + s_k*W1[o,k] + b0[o] + deg*b1[o] via shuffle
// reduce. Deletes the final sb write+read (50MB of traffic) and one dispatch.
__global__ __launch_bounds__(256) void k_lastagg(
    const unsigned short* __restrict__ z, const int* __restrict__ rowstart,
    const int* __restrict__ adj,
    const float* __restrict__ W0, const float* __restrict__ b0,
    const float* __restrict__ W1, const float* __restrict__ b1,
    float* __restrict__ vert, int n) {
    int node = blockIdx.x * 4 + (threadIdx.x >> 6);
    int lane = threadIdx.x & 63;
    if (node >= n) return;
    int r0 = rowstart[node], r1 = rowstart[node + 1];
    float a[8], b[8];
    #pragma unroll
    for (int k = 0; k < 8; ++k) { a[k] = 0.f; b[k] = 0.f; }
    for (int p = r0; p < r1; p += 8) {
        int q = p + (lane & 7);
        int idx = (q < r1) ? adj[q] : 0;
        unsigned int u[8];
        #pragma unroll
        for (int k = 0; k < 8; ++k) {
            int j = __shfl(idx, k);
            u[k] = *(const unsigned int*)&z[(size_t)j * D + lane * 2];
        }
        #pragma unroll
        for (int k = 0; k < 8; ++k)
            if (p + k < r1) acc2(u[k], a[k], b[k]);
    }
    float f0 = ((a[0] + a[1]) + (a[2] + a[3])) + ((a[4] + a[5]) + (a[6] + a[7]));
    float f1 = ((b[0] + b[1]) + (b[2] + b[3])) + ((b[4] + b[5]) + (b[6] + b[7]));
    // own row z[node], cols 2l, 2l+1
    unsigned int zz = *(const unsigned int*)&z[(size_t)node * D + lane * 2];
    float z0, z1;
    { union { unsigned int i; float f; } lo, hi;
      lo.i = zz << 16; hi.i = zz & 0xffff0000u; z0 = lo.f; z1 = hi.f; }
    float dg = (float)(r1 - r0);
    #pragma unroll
    for (int o = 0; o < 3; ++o) {
        float p = z0 * W0[o * D + 2 * lane] + z1 * W0[o * D + 2 * lane + 1]
                + f0 * W1[o * D + 2 * lane] + f1 * W1[o * D + 2 * lane + 1];
        for (int off = 32; off > 0; off >>= 1) p += __shfl_down(p, off);
        if (lane == 0) vert[(size_t)node * 3 + o] = p + b0[o] + dg * b1[o];
    }
}

extern "C" void kernel_launch(void* const* d_in, const int* in_sizes, int n_in,
                              void* d_out, int out_size, void* d_ws, size_t ws_size,
                              hipStream_t stream) {
    const float* features = (const float*)d_in[0];
    const int*   edges    = (const int*)d_in[1];
    const float* W0_1 = (const float*)d_in[2];
    const float* b0_1 = (const float*)d_in[3];
    const float* W1_1 = (const float*)d_in[4];
    const float* b1_1 = (const float*)d_in[5];
    const float* W0_h = (const float*)d_in[6];
    const float* b0_h = (const float*)d_in[7];
    const float* W1_h = (const float*)d_in[8];
    const float* b1_h = (const float*)d_in[9];
    const float* W0_l = (const float*)d_in[10];
    const float* b0_l = (const float*)d_in[11];
    const float* W1_l = (const float*)d_in[12];
    const float* b1_l = (const float*)d_in[13];

    const int N_ = 100000, E_ = 300000;
    float* vert = (float*)d_out;                    // N*3
    float* aux  = (float*)d_out + (size_t)N_ * 3;   // N*128 fp32

    char* w = (char*)d_ws;
    auto alloc = [&](size_t bytes) {
        char* p = w;
        w += (bytes + 255) & ~(size_t)255;
        return p;
    };
    unsigned short* wb    = (unsigned short*)alloc((size_t)13 * 32768 * 2);
    unsigned short* xf    = (unsigned short*)alloc((size_t)N_ * D * 2);
    unsigned short* resid = (unsigned short*)alloc((size_t)N_ * D * 2);
    unsigned short* xa    = (unsigned short*)alloc((size_t)N_ * D * 2);
    unsigned short* xb    = (unsigned short*)alloc((size_t)N_ * D * 2);
    unsigned short* sb    = (unsigned short*)alloc((size_t)N_ * D * 2);
    int* deg    = (int*)alloc((size_t)N_ * 4);
    int* incl   = (int*)alloc((size_t)N_ * 4);
    int* rowst  = (int*)alloc((size_t)(N_ + 1) * 4);
    int* cursor = (int*)alloc((size_t)N_ * 4);
    int* bsum   = (int*)alloc(128 * 4);
    int* adj    = (int*)alloc((size_t)2 * E_ * 4);

    // CSR build
    hipMemsetAsync(deg, 0, (size_t)N_ * 4, stream);
    k_hist<<<(E_ + 255) / 256, 256, 0, stream>>>(edges, E_, deg);
    int nb = (N_ + 1023) / 1024;   // 98
    k_scan1<<<nb, 1024, 0, stream>>>(deg, N_, incl, bsum);
    k_scan2<<<1, 128, 0, stream>>>(bsum, nb);
    k_scan3<<<(N_ + 255) / 256, 256, 0, stream>>>(incl, deg, bsum, N_, 2 * E_, rowst, cursor);
    k_fill<<<(E_ + 255) / 256, 256, 0, stream>>>(edges, E_, cursor, adj);

    // weight + feature conversion
    k_wprep<<<(13 * 2 * 16384 + 255) / 256, 256, 0, stream>>>(W0_1, W1_1, W0_h, W1_h, wb);
    k_cvt<<<(N_ * D / 4 + 255) / 256, 256, 0, stream>>>(features, xf, N_ * D / 4);

    // XCD-chunked grids: xcd = blockIdx%8, chunk = CHUNK nodes
    int gblocks = 8 * ((CHUNK) / 64);    // 8 * 196 = 1568
    int ablocks = 8 * ((CHUNK) / 4);     // 8 * 3136 = 25088
    int lblocks = (N_ + 3) / 4;          // k_lastagg

    // layer 1: xf -> resid
    k_agg<<<ablocks, 256, 0, stream>>>(xf, rowst, adj, sb, N_);
    k_gemm<<<gblocks, 256, 0, stream>>>(xf, sb, wb, b0_1, b1_1, deg, resid,
                                        nullptr, nullptr, nullptr, N_, 1);

    // 12 hidden layers; layer 12 also writes aux (fp32) and z = resid + x12 -> xf
    for (int h = 0; h < 12; ++h) {
        const unsigned short* in = (h == 0) ? resid : ((h & 1) ? xa : xb);
        unsigned short* outp = (h & 1) ? xb : xa;
        float* o32 = (h == 11) ? aux : nullptr;
        const unsigned short* radd = (h == 11) ? resid : nullptr;
        unsigned short* zo = (h == 11) ? xf : nullptr;
        k_agg<<<ablocks, 256, 0, stream>>>(in, rowst, adj, sb, N_);
        k_gemm<<<gblocks, 256, 0, stream>>>(in, sb, wb + (size_t)(1 + h) * 32768,
                                            b0_h + h * 128, b1_h + h * 128, deg,
                                            outp, o32, radd, zo, N_, 1);
    }

    // last layer fused: z (in xf) -> vertices, aggregation kept in registers
    k_lastagg<<<lblocks, 256, 0, stream>>>(xf, rowst, adj, W0_l, b0_l, W1_l, b1_l,
                                           vert, N_);
}

// Round 9
// 1164.509 us; speedup vs baseline: 1.2699x; 1.0283x over previous
//
#include <hip/hip_runtime.h>
#include <hip/hip_bf16.h>

#define D 128
#define OSTR 136   // LDS row stride (shorts) for epilogue transpose
#define CHUNK 12544  // per-XCD node chunk (multiple of 64); 8*12544 >= N

typedef float f32x4  __attribute__((ext_vector_type(4)));
typedef unsigned int u32x4 __attribute__((ext_vector_type(4)));
typedef __attribute__((ext_vector_type(8))) __bf16 bh8;

union UV { uint4 u; bh8 h; };

__device__ inline float bf2f(unsigned short u) {
    union { unsigned int i; float f; } x; x.i = ((unsigned int)u) << 16; return x.f;
}
__device__ inline unsigned short f2bf(float f) {
    union { float f; unsigned int i; } x; x.f = f;
    return (unsigned short)((x.i + 0x7fffu + ((x.i >> 16) & 1u)) >> 16);
}
__device__ inline unsigned int addb2(unsigned int ua, unsigned int ub) {
    union { unsigned int i; float f; } la, ha, lb, hb;
    la.i = ua << 16; ha.i = ua & 0xffff0000u;
    lb.i = ub << 16; hb.i = ub & 0xffff0000u;
    return ((unsigned int)f2bf(ha.f + hb.f) << 16) | f2bf(la.f + lb.f);
}

// ---------------- CSR build ----------------
__global__ void k_hist(const int* __restrict__ edges, int E, int* __restrict__ deg) {
    int e = blockIdx.x * blockDim.x + threadIdx.x;
    if (e < E) {
        atomicAdd(&deg[edges[2 * e]], 1);
        atomicAdd(&deg[edges[2 * e + 1]], 1);
    }
}

__global__ void k_scan1(const int* __restrict__ deg, int n,
                        int* __restrict__ incl, int* __restrict__ bsum) {
    __shared__ int lds[1024];
    int t = threadIdx.x;
    int i = blockIdx.x * 1024 + t;
    int v = (i < n) ? deg[i] : 0;
    int cur = v;
    lds[t] = cur;
    __syncthreads();
    for (int off = 1; off < 1024; off <<= 1) {
        int add = (t >= off) ? lds[t - off] : 0;
        __syncthreads();
        cur += add;
        lds[t] = cur;
        __syncthreads();
    }
    if (i < n) incl[i] = cur;
    if (t == 1023) bsum[blockIdx.x] = cur;
}

__global__ void k_scan2(int* __restrict__ bsum, int nb) {
    __shared__ int lds[128];
    int t = threadIdx.x;
    int v = (t < nb) ? bsum[t] : 0;
    int cur = v;
    lds[t] = cur;
    __syncthreads();
    for (int off = 1; off < 128; off <<= 1) {
        int add = (t >= off) ? lds[t - off] : 0;
        __syncthreads();
        cur += add;
        lds[t] = cur;
        __syncthreads();
    }
    if (t < nb) bsum[t] = cur - v;  // exclusive
}

__global__ void k_scan3(const int* __restrict__ incl, const int* __restrict__ deg,
                        const int* __restrict__ bsum, int n, int twoE,
                        int* __restrict__ rowstart, int* __restrict__ cursor) {
    int i = blockIdx.x * blockDim.x + threadIdx.x;
    if (i < n) {
        int r = incl[i] - deg[i] + bsum[i >> 10];
        rowstart[i] = r;
        cursor[i] = r;
    }
    if (i == 0) rowstart[n] = twoE;
}

__global__ void k_fill(const int* __restrict__ edges, int E,
                       int* __restrict__ cursor, int* __restrict__ adj) {
    int e = blockIdx.x * blockDim.x + threadIdx.x;
    if (e < E) {
        int a = edges[2 * e], b = edges[2 * e + 1];
        adj[atomicAdd(&cursor[a], 1)] = b;
        adj[atomicAdd(&cursor[b], 1)] = a;
    }
}

// ---------------- weight prep: bf16, K-chunked layout ----------------
// wb[l][chunk=kk>>5][o][kk&31], kk = m*128+k (m=0: W0, m=1: W1)
__global__ void k_wprep(const float* __restrict__ W0_1, const float* __restrict__ W1_1,
                        const float* __restrict__ W0_h, const float* __restrict__ W1_h,
                        unsigned short* __restrict__ wb) {
    int idx = blockIdx.x * 256 + threadIdx.x;
    if (idx >= 13 * 2 * 128 * 128) return;
    int k = idx & 127;
    int o = (idx >> 7) & 127;
    int m = (idx >> 14) & 1;
    int l = idx >> 15;
    const float* src = (l == 0) ? (m ? W1_1 : W0_1)
                                : ((m ? W1_h : W0_h) + (size_t)(l - 1) * 16384);
    float v = src[o * 128 + k];
    int kk = m * 128 + k;
    wb[(size_t)l * 32768 + (kk >> 5) * 4096 + o * 32 + (kk & 31)] = f2bf(v);
}

// ---------------- fp32 -> bf16 convert ----------------
__global__ void k_cvt(const float* __restrict__ in, unsigned short* __restrict__ out, int n4) {
    int i = blockIdx.x * blockDim.x + threadIdx.x;
    if (i >= n4) return;
    f32x4 v = *(const f32x4*)&in[(size_t)i * 4];
    unsigned short u[4];
    #pragma unroll
    for (int j = 0; j < 4; ++j) u[j] = f2bf(v[j]);
    *(uint2*)&out[(size_t)i * 4] = *(uint2*)u;
}

// ---------------- neighbor aggregation (bf16 in/out, fp32 accum) ----------------
// wave per node, TWO neighbor rows per load instruction: each lane loads uint2
// (8B = 4 bf16 cols); lanes 0-31 serve even-indexed edges of the batch, lanes
// 32-63 odd ones. Per 8-edge batch: 4 bpermute + 4 loads (vs 8+8 in the 4B/lane
// scheme), loads at the 8B/lane coalescing sweet spot. One shfl_xor(32) combine
// per node at the end. fp32 accumulation per column preserved exactly.
__global__ __launch_bounds__(256) void k_agg(
    const unsigned short* __restrict__ x, const int* __restrict__ rowstart,
    const int* __restrict__ adj, unsigned short* __restrict__ s, int n) {
    int node = (blockIdx.x & 7) * CHUNK + (blockIdx.x >> 3) * 4 + (threadIdx.x >> 6);
    int lane = threadIdx.x & 63;
    if (node >= n) return;
    int r0 = rowstart[node], r1 = rowstart[node + 1];
    int c  = lane & 31;    // column group: bf16 cols 4c..4c+3
    int hi = lane >> 5;    // 0 = even edge of batch, 1 = odd
    float aa0 = 0.f, aa1 = 0.f, aa2 = 0.f, aa3 = 0.f;
    for (int p = r0; p < r1; p += 8) {
        int q = p + (lane & 7);
        int idx = (q < r1) ? adj[q] : adj[r0];
        uint2 u[4];
        #pragma unroll
        for (int k = 0; k < 4; ++k) {
            int j = __shfl(idx, 2 * k + hi);
            u[k] = *(const uint2*)&x[(size_t)j * D + c * 4];
        }
        #pragma unroll
        for (int k = 0; k < 4; ++k) {
            if (p + 2 * k + hi < r1) {
                union { unsigned int i; float f; } t;
                t.i = u[k].x << 16;          aa0 += t.f;
                t.i = u[k].x & 0xffff0000u;  aa1 += t.f;
                t.i = u[k].y << 16;          aa2 += t.f;
                t.i = u[k].y & 0xffff0000u;  aa3 += t.f;
            }
        }
    }
    // combine even/odd partial sums across the two half-waves
    aa0 += __shfl_xor(aa0, 32);
    aa1 += __shfl_xor(aa1, 32);
    aa2 += __shfl_xor(aa2, 32);
    aa3 += __shfl_xor(aa3, 32);
    if (hi == 0) {
        uint2 o;
        o.x = ((unsigned int)f2bf(aa1) << 16) | f2bf(aa0);
        o.y = ((unsigned int)f2bf(aa3) << 16) | f2bf(aa2);
        *(uint2*)&s[(size_t)node * D + c * 4] = o;
    }
}

// ---------------- MFMA GEMM: 64x128 tile, 2-stage register pipeline ----------------
// out[i][o] = act([x_i, s_i] @ [W0T;W1T] + b0 + deg*b1)
// 256 threads = 4 waves; block tile 64 nodes x 128 outs; K=256 in 8 chunks of 32.
// kc loop software-pipelined in REGISTERS: while MFMAs consume stage cs, the 6
// fragment loads of kc+1 are already in flight into stage cs^1. No LDS/barriers
// in the main loop. All stores CACHED (out is 6x-reused by next layer's gather).
__global__ __launch_bounds__(256) void k_gemm(
    const unsigned short* __restrict__ x,   // [n][128] bf16
    const unsigned short* __restrict__ s,   // [n][128] bf16
    const unsigned short* __restrict__ wb,  // layer weights, chunked [8][128][32] bf16
    const float* __restrict__ b0, const float* __restrict__ b1,
    const int* __restrict__ deg,
    unsigned short* __restrict__ out,       // [n][128] bf16
    float* __restrict__ out32,              // optional fp32 copy (aux), may be null
    const unsigned short* __restrict__ resid, // optional residual input (bf16)
    unsigned short* __restrict__ zout,      // optional: zout = out + resid
    int n, int do_relu) {
    __shared__ __align__(16) unsigned short LDS[64 * OSTR];  // 17408 B (epilogue only)
    int node0 = (blockIdx.x & 7) * CHUNK + (blockIdx.x >> 3) * 64;
    if (node0 >= n) return;
    int t = threadIdx.x;
    int lane = t & 63;
    int wave = t >> 6;
    int wm = (wave >> 1) * 32;
    int wn = (wave & 1) * 64;
    int mlane = lane & 15;
    int quad = lane >> 4;

    f32x4 acc[2][4];
    #pragma unroll
    for (int i = 0; i < 2; ++i)
        #pragma unroll
        for (int j = 0; j < 4; ++j) acc[i][j] = (f32x4){0.f, 0.f, 0.f, 0.f};

    uint4 ra[2][2];
    bh8 rb[2][4];
    auto LDK = [&](int kc, int st) {
        const unsigned short* srcA = (kc < 4) ? x : s;
        int kbase = (kc & 3) * 32;
        #pragma unroll
        for (int i = 0; i < 2; ++i) {
            int g = node0 + wm + i * 16 + mlane;
            uint4 v = {0u, 0u, 0u, 0u};
            if (g < n) v = *(const uint4*)&srcA[(size_t)g * D + kbase + quad * 8];
            ra[st][i] = v;
        }
        #pragma unroll
        for (int j = 0; j < 4; ++j)
            rb[st][j] = *(const bh8*)&wb[(size_t)kc * 4096 + (wn + j * 16 + mlane) * 32 + quad * 8];
    };

    LDK(0, 0);
    #pragma unroll
    for (int kc = 0; kc < 8; ++kc) {
        int cs = kc & 1;
        if (kc < 7) LDK(kc + 1, cs ^ 1);   // issue next-chunk loads before MFMAs
        bh8 a0, a1;
        { UV v; v.u = ra[cs][0]; a0 = v.h; }
        { UV v; v.u = ra[cs][1]; a1 = v.h; }
        #pragma unroll
        for (int j = 0; j < 4; ++j) {
            acc[0][j] = __builtin_amdgcn_mfma_f32_16x16x32_bf16(a0, rb[cs][j], acc[0][j], 0, 0, 0);
            acc[1][j] = __builtin_amdgcn_mfma_f32_16x16x32_bf16(a1, rb[cs][j], acc[1][j], 0, 0, 0);
        }
    }

    // ---- epilogue: bias + deg*b1 + relu -> LDS transpose -> coalesced stores ----
    #pragma unroll
    for (int i = 0; i < 2; ++i) {
        int mrow = wm + i * 16 + quad * 4;
        #pragma unroll
        for (int j = 0; j < 4; ++j) {
            int nn = wn + j * 16 + mlane;
            float b0v = b0[nn], b1v = b1[nn];
            #pragma unroll
            for (int r = 0; r < 4; ++r) {
                int g = node0 + mrow + r;
                float dg = (g < n) ? (float)deg[g] : 0.f;
                float val = acc[i][j][r] + b0v + dg * b1v;
                if (do_relu) val = fmaxf(val, 0.f);
                LDS[(mrow + r) * OSTR + nn] = f2bf(val);
            }
        }
    }
    __syncthreads();
    // bf16 store: 4 passes, 16 lanes x 16B = one full 256B node row per 16 threads
    #pragma unroll
    for (int pass = 0; pass < 4; ++pass) {
        int row = pass * 16 + (t >> 4);
        int seg = (t & 15) * 8;
        int g = node0 + row;
        if (g < n) {
            u32x4 v = *(const u32x4*)&LDS[row * OSTR + seg];
            *(u32x4*)&out[(size_t)g * D + seg] = v;
            if (zout) {
                u32x4 rr = *(const u32x4*)&resid[(size_t)g * D + seg];
                u32x4 zz;
                zz.x = addb2(v.x, rr.x);
                zz.y = addb2(v.y, rr.y);
                zz.z = addb2(v.z, rr.z);
                zz.w = addb2(v.w, rr.w);
                *(u32x4*)&zout[(size_t)g * D + seg] = zz;
            }
        }
    }
    if (out32) {
        #pragma unroll
        for (int pass = 0; pass < 8; ++pass) {
            int row = pass * 8 + (t >> 5);
            int seg = (t & 31) * 4;
            int g = node0 + row;
            if (g < n) {
                f32x4 v;
                #pragma unroll
                for (int j = 0; j < 4; ++j) v[j] = bf2f(LDS[row * OSTR + seg + j]);
                *(f32x4*)&out32[(size_t)g * D + seg] = v;
            }
        }
    }
}

// ---------------- fused final layer: aggregate in registers + D_out=3 dot ----------------
// wave per node, same two-rows-per-load gather as k_agg; lane holds 4 cols.
// vert[o] = sum_k z_k*W0[o,k] + s_k*W1[o,k] + b0[o] + deg*b1[o] via 5-step
// half-wave shuffle reduce. Deletes the final sb round-trip and one dispatch.
__global__ __launch_bounds__(256) void k_lastagg(
    const unsigned short* __restrict__ z, const int* __restrict__ rowstart,
    const int* __restrict__ adj,
    const float* __restrict__ W0, const float* __restrict__ b0,
    const float* __restrict__ W1, const float* __restrict__ b1,
    float* __restrict__ vert, int n) {
    int node = blockIdx.x * 4 + (threadIdx.x >> 6);
    int lane = threadIdx.x & 63;
    if (node >= n) return;
    int r0 = rowstart[node], r1 = rowstart[node + 1];
    int c  = lane & 31;
    int hi = lane >> 5;
    float aa0 = 0.f, aa1 = 0.f, aa2 = 0.f, aa3 = 0.f;
    for (int p = r0; p < r1; p += 8) {
        int q = p + (lane & 7);
        int idx = (q < r1) ? adj[q] : adj[r0];
        uint2 u[4];
        #pragma unroll
        for (int k = 0; k < 4; ++k) {
            int j = __shfl(idx, 2 * k + hi);
            u[k] = *(const uint2*)&z[(size_t)j * D + c * 4];
        }
        #pragma unroll
        for (int k = 0; k < 4; ++k) {
            if (p + 2 * k + hi < r1) {
                union { unsigned int i; float f; } t;
                t.i = u[k].x << 16;          aa0 += t.f;
                t.i = u[k].x & 0xffff0000u;  aa1 += t.f;
                t.i = u[k].y << 16;          aa2 += t.f;
                t.i = u[k].y & 0xffff0000u;  aa3 += t.f;
            }
        }
    }
    aa0 += __shfl_xor(aa0, 32);
    aa1 += __shfl_xor(aa1, 32);
    aa2 += __shfl_xor(aa2, 32);
    aa3 += __shfl_xor(aa3, 32);
    // own row z[node], cols 4c..4c+3 (both halves load identical values)
    uint2 zz = *(const uint2*)&z[(size_t)node * D + c * 4];
    float z0, z1, z2, z3;
    { union { unsigned int i; float f; } t;
      t.i = zz.x << 16;         z0 = t.f;
      t.i = zz.x & 0xffff0000u; z1 = t.f;
      t.i = zz.y << 16;         z2 = t.f;
      t.i = zz.y & 0xffff0000u; z3 = t.f; }
    float dg = (float)(r1 - r0);
    #pragma unroll
    for (int o = 0; o < 3; ++o) {
        f32x4 w0 = *(const f32x4*)&W0[o * D + 4 * c];
        f32x4 w1 = *(const f32x4*)&W1[o * D + 4 * c];
        float p = z0 * w0[0] + z1 * w0[1] + z2 * w0[2] + z3 * w0[3]
                + aa0 * w1[0] + aa1 * w1[1] + aa2 * w1[2] + aa3 * w1[3];
        p += __shfl_xor(p, 16);
        p += __shfl_xor(p, 8);
        p += __shfl_xor(p, 4);
        p += __shfl_xor(p, 2);
        p += __shfl_xor(p, 1);
        if (lane == 0) vert[(size_t)node * 3 + o] = p + b0[o] + dg * b1[o];
    }
}

extern "C" void kernel_launch(void* const* d_in, const int* in_sizes, int n_in,
                              void* d_out, int out_size, void* d_ws, size_t ws_size,
                              hipStream_t stream) {
    const float* features = (const float*)d_in[0];
    const int*   edges    = (const int*)d_in[1];
    const float* W0_1 = (const float*)d_in[2];
    const float* b0_1 = (const float*)d_in[3];
    const float* W1_1 = (const float*)d_in[4];
    const float* b1_1 = (const float*)d_in[5];
    const float* W0_h = (const float*)d_in[6];
    const float* b0_h = (const float*)d_in[7];
    const float* W1_h = (const float*)d_in[8];
    const float* b1_h = (const float*)d_in[9];
    const float* W0_l = (const float*)d_in[10];
    const float* b0_l = (const float*)d_in[11];
    const float* W1_l = (const float*)d_in[12];
    const float* b1_l = (const float*)d_in[13];

    const int N_ = 100000, E_ = 300000;
    float* vert = (float*)d_out;                    // N*3
    float* aux  = (float*)d_out + (size_t)N_ * 3;   // N*128 fp32

    char* w = (char*)d_ws;
    auto alloc = [&](size_t bytes) {
        char* p = w;
        w += (bytes + 255) & ~(size_t)255;
        return p;
    };
    unsigned short* wb    = (unsigned short*)alloc((size_t)13 * 32768 * 2);
    unsigned short* xf    = (unsigned short*)alloc((size_t)N_ * D * 2);
    unsigned short* resid = (unsigned short*)alloc((size_t)N_ * D * 2);
    unsigned short* xa    = (unsigned short*)alloc((size_t)N_ * D * 2);
    unsigned short* xb    = (unsigned short*)alloc((size_t)N_ * D * 2);
    unsigned short* sb    = (unsigned short*)alloc((size_t)N_ * D * 2);
    int* deg    = (int*)alloc((size_t)N_ * 4);
    int* incl   = (int*)alloc((size_t)N_ * 4);
    int* rowst  = (int*)alloc((size_t)(N_ + 1) * 4);
    int* cursor = (int*)alloc((size_t)N_ * 4);
    int* bsum   = (int*)alloc(128 * 4);
    int* adj    = (int*)alloc((size_t)2 * E_ * 4);

    // CSR build
    hipMemsetAsync(deg, 0, (size_t)N_ * 4, stream);
    k_hist<<<(E_ + 255) / 256, 256, 0, stream>>>(edges, E_, deg);
    int nb = (N_ + 1023) / 1024;   // 98
    k_scan1<<<nb, 1024, 0, stream>>>(deg, N_, incl, bsum);
    k_scan2<<<1, 128, 0, stream>>>(bsum, nb);
    k_scan3<<<(N_ + 255) / 256, 256, 0, stream>>>(incl, deg, bsum, N_, 2 * E_, rowst, cursor);
    k_fill<<<(E_ + 255) / 256, 256, 0, stream>>>(edges, E_, cursor, adj);

    // weight + feature conversion
    k_wprep<<<(13 * 2 * 16384 + 255) / 256, 256, 0, stream>>>(W0_1, W1_1, W0_h, W1_h, wb);
    k_cvt<<<(N_ * D / 4 + 255) / 256, 256, 0, stream>>>(features, xf, N_ * D / 4);

    // XCD-chunked grids: xcd = blockIdx%8, chunk = CHUNK nodes
    int gblocks = 8 * ((CHUNK) / 64);    // 8 * 196 = 1568
    int ablocks = 8 * ((CHUNK) / 4);     // 8 * 3136 = 25088
    int lblocks = (N_ + 3) / 4;          // k_lastagg

    // layer 1: xf -> resid
    k_agg<<<ablocks, 256, 0, stream>>>(xf, rowst, adj, sb, N_);
    k_gemm<<<gblocks, 256, 0, stream>>>(xf, sb, wb, b0_1, b1_1, deg, resid,
                                        nullptr, nullptr, nullptr, N_, 1);

    // 12 hidden layers; layer 12 also writes aux (fp32) and z = resid + x12 -> xf
    for (int h = 0; h < 12; ++h) {
        const unsigned short* in = (h == 0) ? resid : ((h & 1) ? xa : xb);
        unsigned short* outp = (h & 1) ? xb : xa;
        float* o32 = (h == 11) ? aux : nullptr;
        const unsigned short* radd = (h == 11) ? resid : nullptr;
        unsigned short* zo = (h == 11) ? xf : nullptr;
        k_agg<<<ablocks, 256, 0, stream>>>(in, rowst, adj, sb, N_);
        k_gemm<<<gblocks, 256, 0, stream>>>(in, sb, wb + (size_t)(1 + h) * 32768,
                                            b0_h + h * 128, b1_h + h * 128, deg,
                                            outp, o32, radd, zo, N_, 1);
    }

    // last layer fused: z (in xf) -> vertices, aggregation kept in registers
    k_lastagg<<<lblocks, 256, 0, stream>>>(xf, rowst, adj, W0_l, b0_l, W1_l, b1_l,
                                           vert, N_);
}